// Round 4
// baseline (364.970 us; speedup 1.0000x reference)
//
#include <hip/hip_runtime.h>

typedef unsigned short u16;
typedef short bf16x8 __attribute__((ext_vector_type(8)));
typedef float f32x4 __attribute__((ext_vector_type(4)));

__device__ __forceinline__ float b2f(u16 u){ return __uint_as_float(((unsigned)u)<<16); }
__device__ __forceinline__ u16 f2bf(float f){ return (u16)((__float_as_uint(f)+0x8000u)>>16); }
__device__ __forceinline__ float ldf(const void* p, int i, bool isbf){
  return isbf ? b2f(((const u16*)p)[i]) : ((const float*)p)[i];
}
__device__ __forceinline__ void ld8(u16* dst, const void* p, int i, bool isbf){
  if (isbf) { *(uint4*)dst = *(const uint4*)((const u16*)p + i); }
  else {
    float4 a = *(const float4*)((const float*)p + i);
    float4 b = *(const float4*)((const float*)p + i + 4);
    dst[0]=f2bf(a.x); dst[1]=f2bf(a.y); dst[2]=f2bf(a.z); dst[3]=f2bf(a.w);
    dst[4]=f2bf(b.x); dst[5]=f2bf(b.y); dst[6]=f2bf(b.z); dst[7]=f2bf(b.w);
  }
}
__device__ __forceinline__ float c8(const float* __restrict__ p, int i, int stride){
  float s = 0.f;
  #pragma unroll
  for (int k = 0; k < 8; k++) s += p[i + k*stride];
  return s;
}
#define MFMA16(a,b,c) __builtin_amdgcn_mfma_f32_16x16x32_bf16((a),(b),(c),0,0,0)

// ---------------------------------------------------------------------------
// dtype detector: bf16 vs f32 by exponent plausibility of first 4096 u16 words
// ---------------------------------------------------------------------------
__global__ __launch_bounds__(256) void detect_kernel(const u16* __restrict__ h, int* __restrict__ flag) {
  int tid = threadIdx.x;
  int cnt = 0;
  for (int i = tid; i < 4096; i += 256) {
    int e = (h[i] >> 7) & 0xFF;
    cnt += (e >= 116 && e <= 132) ? 1 : 0;
  }
  __shared__ int sh[256];
  sh[tid] = cnt; __syncthreads();
  for (int s = 128; s > 0; s >>= 1) { if (tid < s) sh[tid] += sh[tid + s]; __syncthreads(); }
  if (tid == 0) flag[0] = (sh[0] >= 3100) ? 1 : 0;
}

// ---------------------------------------------------------------------------
// cos/sin table: ctab[t][dm], t in [0,4032), dm in [0,64)
// ---------------------------------------------------------------------------
__global__ __launch_bounds__(256) void ctab_kernel(float2* __restrict__ ctab) {
  int idx = blockIdx.x * 256 + threadIdx.x;       // 258048 exact
  int dm = idx & 63, t = idx >> 6;
  float f = exp2f(-(float)dm * (13.287712379549449f / 64.0f));
  float ang = (float)t * f;
  float s, c;
  sincosf(ang, &s, &c);
  ctab[idx] = make_float2(c, s);
}

// ---------------------------------------------------------------------------
// Split-K projection: partial[ks][64][ostride] = X[64][512-slice] . W^T
// grid (Ntot/32, 8). 32 n-cols per block, 4 k-iters, 8 MFMA/wave/iter.
// ---------------------------------------------------------------------------
__global__ __launch_bounds__(256) void proj_kernel(
    const void* __restrict__ X, const void* __restrict__ Wa,
    const void* __restrict__ Wb, const void* __restrict__ Wc,
    float* __restrict__ out32, int Na, int Nb, int ostride,
    const int* __restrict__ flagp, int x_dyn)
{
  bool fbf = (*flagp != 0);
  bool xbf = x_dyn ? fbf : true;
  int n0 = blockIdx.x * 32;
  int ks0 = blockIdx.y * 512;
  const void* W; int wr0;
  if (n0 < Na)           { W = Wa; wr0 = n0; }
  else if (n0 < Na + Nb) { W = Wb; wr0 = n0 - Na; }
  else                   { W = Wc; wr0 = n0 - Na - Nb; }

  __shared__ u16 Xs[64][136];
  __shared__ u16 Ws[32][136];
  int tid = threadIdx.x;
  int wv = tid >> 6, lane = tid & 63, lr = lane & 15, lq = lane >> 4;
  f32x4 acc0 = {0.f,0.f,0.f,0.f}, acc1 = {0.f,0.f,0.f,0.f};

  for (int ki = 0; ki < 4; ki++) {
    int k0 = ks0 + ki * 128;
    __syncthreads();
    for (int u = tid; u < 1024; u += 256) {       // X tile 64x128
      int row = u >> 4, cc = u & 15;
      ld8(&Xs[row][cc * 8], X, row * 4096 + k0 + cc * 8, xbf);
    }
    for (int u = tid; u < 512; u += 256) {        // W tile 32x128
      int row = u >> 4, cc = u & 15;
      ld8(&Ws[row][cc * 8], W, (wr0 + row) * 4096 + k0 + cc * 8, fbf);
    }
    __syncthreads();
    #pragma unroll
    for (int ks = 0; ks < 4; ks++) {
      bf16x8 af = *(const bf16x8*)&Xs[wv * 16 + lr][ks * 32 + lq * 8];
      bf16x8 b0 = *(const bf16x8*)&Ws[lr][ks * 32 + lq * 8];
      bf16x8 b1 = *(const bf16x8*)&Ws[16 + lr][ks * 32 + lq * 8];
      acc0 = MFMA16(af, b0, acc0);
      acc1 = MFMA16(af, b1, acc1);
    }
  }
  float* outp = out32 + (size_t)blockIdx.y * 64 * ostride;
  #pragma unroll
  for (int r = 0; r < 4; r++) {
    outp[(wv * 16 + lq * 4 + r) * ostride + n0 + lr]      = acc0[r];
    outp[(wv * 16 + lq * 4 + r) * ostride + n0 + 16 + lr] = acc1[r];
  }
}

// ---------------------------------------------------------------------------
// Prep: RoPE'd Q [bh][32][128], RoPE'd full-K [bh][64][128], V_full^T [bh][128][64]
// ---------------------------------------------------------------------------
__global__ __launch_bounds__(256) void prep_kernel(
    const float* __restrict__ Cq32, const void* __restrict__ kfp, const void* __restrict__ vfp,
    const float2* __restrict__ ctab, const int* __restrict__ flagp,
    u16* __restrict__ qrb, u16* __restrict__ kfullb, u16* __restrict__ vfullT)
{
  bool isbf = (*flagp != 0);
  int idx = blockIdx.x * 256 + threadIdx.x;       // 1,310,720 exact
  if (idx < 262144) {                              // qr
    int d = idx & 127, row = (idx >> 7) & 31, bh = idx >> 12;
    int b = bh >> 3, kvh = bh & 7, g = row >> 3, qp = row & 7;
    int tok = b * 8 + qp, h = kvh * 4 + g;
    float x  = c8(Cq32, tok * 6144 + h * 128 + d, 393216);
    float x2 = c8(Cq32, tok * 6144 + h * 128 + (d ^ 64), 393216);
    float2 cs = ctab[(4024 + qp) * 64 + (d & 63)];
    float sgn = (d < 64) ? -1.f : 1.f;
    qrb[idx] = f2bf(x * cs.x + sgn * (x2 * cs.y));
  } else if (idx < 786432) {                       // k_full roped, pos = 3968+t
    int j = idx - 262144;
    int d = j & 127, t = (j >> 7) & 63, bh = j >> 13;
    int b = bh >> 3, kvh = bh & 7;
    float x, x2;
    if (t < 56) {
      x  = ldf(kfp, (bh * 56 + t) * 128 + d, isbf);
      x2 = ldf(kfp, (bh * 56 + t) * 128 + (d ^ 64), isbf);
    } else {
      int tok = b * 8 + (t - 56);
      x  = c8(Cq32, tok * 6144 + 4096 + kvh * 128 + d, 393216);
      x2 = c8(Cq32, tok * 6144 + 4096 + kvh * 128 + (d ^ 64), 393216);
    }
    float2 cs = ctab[(3968 + t) * 64 + (d & 63)];
    float sgn = (d < 64) ? -1.f : 1.f;
    kfullb[j] = f2bf(x * cs.x + sgn * (x2 * cs.y));
  } else {                                         // v_full transposed [bh][d][t]
    int j = idx - 786432;
    int t = j & 63, d = (j >> 6) & 127, bh = j >> 13;
    int b = bh >> 3, kvh = bh & 7;
    float x;
    if (t < 56) x = ldf(vfp, (bh * 56 + t) * 128 + d, isbf);
    else        x = c8(Cq32, (b * 8 + t - 56) * 6144 + 5120 + kvh * 128 + d, 393216);
    vfullT[j] = f2bf(x);
  }
}

// ---------------------------------------------------------------------------
// Online-flash attention, 64-key chunks, 2 per block. Grid (64 bh, 32 grp).
// Chunks 0..61 quantized; chunk 62 = 64 full-precision keys; 63 skipped.
// Register softmax (shuffle) + tiny LDS stats; two-stage coalesced raw
// staging for quant words/scales. LDS = 31232 B -> 5 blocks/CU.
// ---------------------------------------------------------------------------
__global__ __launch_bounds__(256, 5) void attn_kernel(
    const int* __restrict__ kqw, const void* __restrict__ ksc, const void* __restrict__ kmn,
    const int* __restrict__ vqw, const void* __restrict__ vsc, const void* __restrict__ vmn,
    const u16* __restrict__ qrb, const u16* __restrict__ kfullb, const u16* __restrict__ vfullT,
    const float2* __restrict__ ctab, const int* __restrict__ flagp,
    u16* __restrict__ Opart, float* __restrict__ ml)
{
  bool isbf = (*flagp != 0);
  int bh = blockIdx.x, grp = blockIdx.y;
  int tid = threadIdx.x;

  __shared__ __align__(16) unsigned char L[31232];
  u16 (*Ktile)[136] = (u16(*)[136])L;              // [64][136]  17408 B (lifetime: B..C1)
  u16 (*Vtile)[72]  = (u16(*)[72])L;               // [128][72]  18432 B (lifetime: C1..loop-end)
  unsigned* rawK = (unsigned*)(L + 18432);         // [128][9]    4608 B (phase0..C1)
  float* sK  = (float*)(L + 23040);                // [128][3]    1536
  float* sKm = (float*)(L + 24576);                // [128][3]    1536
  unsigned* rawV = (unsigned*)(L + 18432);         // [64][17]    4352 (C1..D, overlays rawK)
  float* sV  = (float*)(L + 22784);                // [64][5]     1280
  float* sVm = (float*)(L + 24064);                // [64][5]     1280
  u16 (*Pl)[72] = (u16(*)[72])(L + 26112);         // [32][72]    4608 (C1..loop-end)
  float* pmax = (float*)(L + 30720);               // [4][16]
  float* psum = (float*)(L + 30976);               // [4][16]

  int wv = tid >> 6, lane = tid & 63, lr = lane & 15, lq = lane >> 4;
  int mt = wv & 1, nh = wv >> 1;

  bf16x8 qa[4];
  #pragma unroll
  for (int ks = 0; ks < 4; ks++)
    qa[ks] = *(const bf16x8*)&qrb[(bh * 32 + mt * 16 + lr) * 128 + ks * 32 + lq * 8];

  float m_prev[4], l_run[4];
  #pragma unroll
  for (int r = 0; r < 4; r++) { m_prev[r] = -INFINITY; l_run[r] = 0.f; }
  f32x4 zf = {0.f,0.f,0.f,0.f};
  f32x4 oacc[4] = {zf, zf, zf, zf};

  for (int j = 0; j < 2; j++) {
    int c = grp * 2 + j;
    if (c >= 63) break;                            // uniform per block
    bool fullc = (c == 62);

    // ---- phase 0: coalesced raw K words + scales -> LDS ----
    if (!fullc) {
      #pragma unroll
      for (int it = 0; it < 4; it++) {
        int idx = tid + 256 * it;
        int d = idx >> 3, w = idx & 7;             // 8 lanes/row -> 32B segments
        rawK[d * 9 + w] = (unsigned)kqw[(bh * 128 + d) * 496 + c * 8 + w];
      }
      { int d = tid >> 1, gi = tid & 1;
        sK[d * 3 + gi]  = ldf(ksc, (bh * 128 + d) * 124 + c * 2 + gi, isbf);
        sKm[d * 3 + gi] = ldf(kmn, (bh * 128 + d) * 124 + c * 2 + gi, isbf); }
    }
    __syncthreads();                               // A
    // ---- dequant+RoPE K -> Ktile[t][d] (or stage full K) ----
    if (!fullc) {
      #pragma unroll
      for (int it = 0; it < 4; it++) {
        int idx = tid + 256 * it;
        int d = idx & 127, w = idx >> 7;           // w<8; lanes vary d
        unsigned w1 = rawK[d * 9 + w];
        unsigned w2 = rawK[(d ^ 64) * 9 + w];
        int gi = w >> 2;
        float sc1 = sK[d * 3 + gi],        m1 = sKm[d * 3 + gi];
        float sc2 = sK[(d ^ 64) * 3 + gi], m2 = sKm[(d ^ 64) * 3 + gi];
        int dm = d & 63;
        float sgn = (d < 64) ? -1.f : 1.f;
        const float2* ct = &ctab[(c * 64 + w * 8) * 64 + dm];
        #pragma unroll
        for (int i = 0; i < 8; i++) {
          float v1 = (float)((w1 >> (4 * i)) & 15u) * sc1 + m1;
          float v2 = (float)((w2 >> (4 * i)) & 15u) * sc2 + m2;
          float2 cs = ct[i * 64];
          Ktile[w * 8 + i][d] = f2bf(v1 * cs.x + sgn * (v2 * cs.y));
        }
      }
    } else {
      for (int u = tid; u < 1024; u += 256) {
        int row = u >> 4, cc = u & 15;
        *(uint4*)&Ktile[row][cc * 8] = *(const uint4*)&kfullb[(bh * 64 + row) * 128 + cc * 8];
      }
    }
    __syncthreads();                               // B
    // ---- S = Q.K^T : rows mt*16+, cols nh*32 + nt*16 + lr ----
    f32x4 sacc[2] = {zf, zf};
    #pragma unroll
    for (int ks = 0; ks < 4; ks++) {
      #pragma unroll
      for (int nt = 0; nt < 2; nt++) {
        bf16x8 bfr = *(const bf16x8*)&Ktile[nh * 32 + nt * 16 + lr][ks * 32 + lq * 8];
        sacc[nt] = MFMA16(qa[ks], bfr, sacc[nt]);
      }
    }
    // scale + wave-local row max (over nt regs and 16 lr lanes)
    float mx[4];
    #pragma unroll
    for (int r = 0; r < 4; r++) {
      sacc[0][r] *= 0.08838834764831845f;
      sacc[1][r] *= 0.08838834764831845f;
      mx[r] = fmaxf(sacc[0][r], sacc[1][r]);
    }
    #pragma unroll
    for (int m = 1; m < 16; m <<= 1) {
      #pragma unroll
      for (int r = 0; r < 4; r++) mx[r] = fmaxf(mx[r], __shfl_xor(mx[r], m));
    }
    if (lr == 0) {
      #pragma unroll
      for (int r = 0; r < 4; r++) pmax[wv * 16 + lq * 4 + r] = mx[r];
    }
    __syncthreads();                               // C1 (Ktile/rawK/sK dead)
    // ---- stage raw V + scales (overlay dead region) / full V -> Vtile ----
    if (!fullc) {
      #pragma unroll
      for (int it = 0; it < 4; it++) {
        int idx = tid + 256 * it;                  // fully coalesced
        int t = idx >> 4, w = idx & 15;
        rawV[t * 17 + w] = (unsigned)vqw[(bh * 3968 + c * 64 + t) * 16 + w];
      }
      { int t = tid >> 2, gq = tid & 3;            // fully coalesced
        sV[t * 5 + gq]  = ldf(vsc, (bh * 3968 + c * 64 + t) * 4 + gq, isbf);
        sVm[t * 5 + gq] = ldf(vmn, (bh * 3968 + c * 64 + t) * 4 + gq, isbf); }
    } else {
      for (int u = tid; u < 1024; u += 256) {
        int d = u >> 3, t8 = u & 7;
        *(uint4*)&Vtile[d][t8 * 8] = *(const uint4*)&vfullT[(bh * 128 + d) * 64 + t8 * 8];
      }
    }
    // ---- online softmax: merge chunk max, exp, P write, partial sums ----
    float alpha[4], osum[4];
    #pragma unroll
    for (int r = 0; r < 4; r++) {
      float cm = fmaxf(mx[r], pmax[(wv ^ 2) * 16 + lq * 4 + r]);
      float mn2 = fmaxf(m_prev[r], cm);
      alpha[r] = __expf(m_prev[r] - mn2);          // 0 on first chunk
      m_prev[r] = mn2;
    }
    u16 pb[2][4];
    #pragma unroll
    for (int r = 0; r < 4; r++) {
      float p0 = __expf(sacc[0][r] - m_prev[r]);
      float p1 = __expf(sacc[1][r] - m_prev[r]);
      pb[0][r] = f2bf(p0); pb[1][r] = f2bf(p1);
      osum[r] = b2f(pb[0][r]) + b2f(pb[1][r]);     // sum what PV uses
    }
    #pragma unroll
    for (int m = 1; m < 16; m <<= 1) {
      #pragma unroll
      for (int r = 0; r < 4; r++) osum[r] += __shfl_xor(osum[r], m);
    }
    #pragma unroll
    for (int nt = 0; nt < 2; nt++)
      #pragma unroll
      for (int r = 0; r < 4; r++)
        Pl[mt * 16 + lq * 4 + r][nh * 32 + nt * 16 + lr] = pb[nt][r];
    if (lr == 0) {
      #pragma unroll
      for (int r = 0; r < 4; r++) psum[wv * 16 + lq * 4 + r] = osum[r];
    }
    __syncthreads();                               // C2
    // ---- dequant V -> Vtile[d][t] ----
    if (!fullc) {
      #pragma unroll
      for (int it = 0; it < 4; it++) {
        int idx = tid + 256 * it;
        int tl = idx & 63, w = idx >> 6;           // w<16; lanes vary t
        unsigned wd = rawV[tl * 17 + w];
        int gq = w >> 2;
        float sc = sV[tl * 5 + gq], mn = sVm[tl * 5 + gq];
        #pragma unroll
        for (int i = 0; i < 8; i++)
          Vtile[w * 8 + i][tl] = f2bf((float)((wd >> (4 * i)) & 15u) * sc + mn);
      }
    }
    // l update (partner psum ready at C2)
    #pragma unroll
    for (int r = 0; r < 4; r++)
      l_run[r] = l_run[r] * alpha[r] + osum[r] + psum[(wv ^ 2) * 16 + lq * 4 + r];
    __syncthreads();                               // D
    // ---- O = O*alpha + P.V ----
    f32x4 pv[4] = {zf, zf, zf, zf};
    #pragma unroll
    for (int ks = 0; ks < 2; ks++) {
      bf16x8 af = *(const bf16x8*)&Pl[mt * 16 + lr][ks * 32 + lq * 8];
      #pragma unroll
      for (int nt = 0; nt < 4; nt++) {
        bf16x8 bfr = *(const bf16x8*)&Vtile[nh * 64 + nt * 16 + lr][ks * 32 + lq * 8];
        pv[nt] = MFMA16(af, bfr, pv[nt]);
      }
    }
    #pragma unroll
    for (int nt = 0; nt < 4; nt++)
      #pragma unroll
      for (int r = 0; r < 4; r++)
        oacc[nt][r] = oacc[nt][r] * alpha[r] + pv[nt][r];
  }

  u16* Ob = Opart + (size_t)((bh * 32 + grp) * 32) * 128;
  #pragma unroll
  for (int nt = 0; nt < 4; nt++)
    #pragma unroll
    for (int r = 0; r < 4; r++)
      Ob[(mt * 16 + lq * 4 + r) * 128 + nh * 64 + nt * 16 + lr] = f2bf(oacc[nt][r]);
  if (wv < 2 && lr == 0) {
    #pragma unroll
    for (int r = 0; r < 4; r++) {
      ml[((bh * 32 + grp) * 32 + mt * 16 + lq * 4 + r) * 2 + 0] = m_prev[r];
      ml[((bh * 32 + grp) * 32 + mt * 16 + lq * 4 + r) * 2 + 1] = l_run[r];
    }
  }
}

// ---------------------------------------------------------------------------
// Combine 32 group partials per bh. Grid (64, 4 d-quarters).
// ---------------------------------------------------------------------------
__global__ __launch_bounds__(256) void combine_kernel(
    const u16* __restrict__ Opart, const float* __restrict__ ml, u16* __restrict__ attn_out)
{
  int bh = blockIdx.x, dq = blockIdx.y, tid = threadIdx.x;
  __shared__ float Wg[32][33];
  __shared__ float Ls[32];
  if (tid < 32) {
    int row = tid;
    float M = -INFINITY;
    for (int g = 0; g < 32; g++)
      M = fmaxf(M, ml[((bh * 32 + g) * 32 + row) * 2]);
    float Lacc = 0.f;
    for (int g = 0; g < 32; g++) {
      float m = ml[((bh * 32 + g) * 32 + row) * 2];
      float l = ml[((bh * 32 + g) * 32 + row) * 2 + 1];
      float w = __expf(m - M);
      Wg[g][row] = w;
      Lacc += l * w;
    }
    Ls[row] = Lacc;
  }
  __syncthreads();
  int row = tid >> 3, ds = tid & 7;
  int d0 = dq * 32 + ds * 4;
  float a0 = 0.f, a1 = 0.f, a2 = 0.f, a3 = 0.f;
  for (int g = 0; g < 32; g++) {
    float w = Wg[g][row];
    const u16* p = Opart + (size_t)((bh * 32 + g) * 32 + row) * 128 + d0;
    uint2 v = *(const uint2*)p;
    const u16* h = (const u16*)&v;
    a0 += w * b2f(h[0]); a1 += w * b2f(h[1]); a2 += w * b2f(h[2]); a3 += w * b2f(h[3]);
  }
  float inv = 1.0f / Ls[row];
  int b = bh >> 3, kvh = bh & 7, hg = row >> 3, qp = row & 7;
  u16* dst = attn_out + (size_t)(b * 8 + qp) * 4096 + (kvh * 4 + hg) * 128 + d0;
  dst[0] = f2bf(a0 * inv); dst[1] = f2bf(a1 * inv);
  dst[2] = f2bf(a2 * inv); dst[3] = f2bf(a3 * inv);
}

// ---------------------------------------------------------------------------
// Sum 8 Wo K-split partials, emit final output in detected dtype.
// ---------------------------------------------------------------------------
__global__ __launch_bounds__(256) void cast_kernel(
    const float* __restrict__ O32, const int* __restrict__ flagp, void* __restrict__ out)
{
  int i = blockIdx.x * 256 + threadIdx.x;          // 262144 exact
  float v = c8(O32, i, 262144);
  if (*flagp) ((u16*)out)[i] = f2bf(v);
  else        ((float*)out)[i] = v;
}

// ---------------------------------------------------------------------------
extern "C" void kernel_launch(void* const* d_in, const int* in_sizes, int n_in,
                              void* d_out, int out_size, void* d_ws, size_t ws_size,
                              hipStream_t stream)
{
  const void* hidden = d_in[0];
  const void* Wq  = d_in[1];
  const void* Wk  = d_in[2];
  const void* Wv  = d_in[3];
  const void* Wo  = d_in[4];
  const int*  kqw = (const int*)d_in[5];
  const void* ksc = d_in[6];
  const void* kmn = d_in[7];
  const void* kfp = d_in[8];
  const int*  vqw = (const int*)d_in[9];
  const void* vsc = d_in[10];
  const void* vmn = d_in[11];
  const void* vfp = d_in[12];

  char* ws = (char*)d_ws;
  int*    flag     = (int*)(ws);                    //        256
  float2* ctab     = (float2*)(ws + 256);           //  2,064,384
  float*  Cq32     = (float*)(ws + 2064640);        // regionA 16,777,216:
  u16*    Opart    = (u16*)(ws + 2064640);          //   Cq32 12.6MB / Opart 16.8MB / O32 8.4MB
  float*  O32      = (float*)(ws + 2064640);        //   (pairwise-disjoint lifetimes)
  u16*    qrb      = (u16*)(ws + 18841856);         //    524,288 (attn_out overlays)
  u16*    attn_out = qrb;
  u16*    kfullb   = (u16*)(ws + 19366144);         //  1,048,576
  u16*    vfullT   = (u16*)(ws + 20414720);         //  1,048,576
  float*  ml       = (float*)(ws + 21463296);       //    524,288  -> total ~22.0 MB

  detect_kernel<<<1, 256, 0, stream>>>((const u16*)hidden, flag);
  ctab_kernel<<<1008, 256, 0, stream>>>(ctab);
  proj_kernel<<<dim3(192, 8), 256, 0, stream>>>(hidden, Wq, Wk, Wv, Cq32, 4096, 1024, 6144, flag, 1);
  prep_kernel<<<5120, 256, 0, stream>>>(Cq32, kfp, vfp, ctab, flag, qrb, kfullb, vfullT);
  attn_kernel<<<dim3(64, 32), 256, 0, stream>>>(kqw, ksc, kmn, vqw, vsc, vmn,
                                                qrb, kfullb, vfullT, ctab, flag, Opart, ml);
  combine_kernel<<<dim3(64, 4), 256, 0, stream>>>(Opart, ml, attn_out);
  proj_kernel<<<dim3(128, 8), 256, 0, stream>>>(attn_out, Wo, Wo, Wo, O32, 4096, 0, 4096, flag, 0);
  cast_kernel<<<1024, 256, 0, stream>>>(O32, flag, d_out);
}

// Round 5
// 315.535 us; speedup vs baseline: 1.1567x; 1.1567x over previous
//
#include <hip/hip_runtime.h>

typedef unsigned short u16;
typedef short bf16x8 __attribute__((ext_vector_type(8)));
typedef float f32x4 __attribute__((ext_vector_type(4)));

__device__ __forceinline__ float b2f(u16 u){ return __uint_as_float(((unsigned)u)<<16); }
__device__ __forceinline__ u16 f2bf(float f){ return (u16)((__float_as_uint(f)+0x8000u)>>16); }
__device__ __forceinline__ float ldf(const void* p, int i, bool isbf){
  return isbf ? b2f(((const u16*)p)[i]) : ((const float*)p)[i];
}
__device__ __forceinline__ void ld8(u16* dst, const void* p, int i, bool isbf){
  if (isbf) { *(uint4*)dst = *(const uint4*)((const u16*)p + i); }
  else {
    float4 a = *(const float4*)((const float*)p + i);
    float4 b = *(const float4*)((const float*)p + i + 4);
    dst[0]=f2bf(a.x); dst[1]=f2bf(a.y); dst[2]=f2bf(a.z); dst[3]=f2bf(a.w);
    dst[4]=f2bf(b.x); dst[5]=f2bf(b.y); dst[6]=f2bf(b.z); dst[7]=f2bf(b.w);
  }
}
__device__ __forceinline__ float c8(const float* __restrict__ p, int i, int stride){
  float s = 0.f;
  #pragma unroll
  for (int k = 0; k < 8; k++) s += p[i + k*stride];
  return s;
}
#define MFMA16(a,b,c) __builtin_amdgcn_mfma_f32_16x16x32_bf16((a),(b),(c),0,0,0)

// ---------------------------------------------------------------------------
// cos/sin table + (block 0) dtype detection.
// ctab[t][dm], t in [0,4032), dm in [0,64).
// ---------------------------------------------------------------------------
__global__ __launch_bounds__(256) void ctab_kernel(const u16* __restrict__ h,
                                                   int* __restrict__ flag,
                                                   float2* __restrict__ ctab) {
  int tid = threadIdx.x;
  if (blockIdx.x == 0) {                          // dtype detect: bf16 vs f32
    int cnt = 0;
    for (int i = tid; i < 4096; i += 256) {
      int e = (h[i] >> 7) & 0xFF;
      cnt += (e >= 116 && e <= 132) ? 1 : 0;      // |x| in [2^-11, 2^5]
    }
    __shared__ int sh[256];
    sh[tid] = cnt; __syncthreads();
    for (int s = 128; s > 0; s >>= 1) { if (tid < s) sh[tid] += sh[tid + s]; __syncthreads(); }
    if (tid == 0) flag[0] = (sh[0] >= 3100) ? 1 : 0;
  }
  int idx = blockIdx.x * 256 + tid;               // 258048 exact
  int dm = idx & 63, t = idx >> 6;
  float f = exp2f(-(float)dm * (13.287712379549449f / 64.0f));
  float ang = (float)t * f;
  float s, c;
  sincosf(ang, &s, &c);
  ctab[idx] = make_float2(c, s);
}

// ---------------------------------------------------------------------------
// Split-K projection: partial[ks][64][ostride] = X[64][512-slice] . W^T
// grid (Ntot/32, 8). 32 n-cols per block, 4 k-iters, 8 MFMA/wave/iter.
// ---------------------------------------------------------------------------
__global__ __launch_bounds__(256) void proj_kernel(
    const void* __restrict__ X, const void* __restrict__ Wa,
    const void* __restrict__ Wb, const void* __restrict__ Wc,
    float* __restrict__ out32, int Na, int Nb, int ostride,
    const int* __restrict__ flagp, int x_dyn)
{
  bool fbf = (*flagp != 0);
  bool xbf = x_dyn ? fbf : true;
  int n0 = blockIdx.x * 32;
  int ks0 = blockIdx.y * 512;
  const void* W; int wr0;
  if (n0 < Na)           { W = Wa; wr0 = n0; }
  else if (n0 < Na + Nb) { W = Wb; wr0 = n0 - Na; }
  else                   { W = Wc; wr0 = n0 - Na - Nb; }

  __shared__ u16 Xs[64][136];
  __shared__ u16 Ws[32][136];
  int tid = threadIdx.x;
  int wv = tid >> 6, lane = tid & 63, lr = lane & 15, lq = lane >> 4;
  f32x4 acc0 = {0.f,0.f,0.f,0.f}, acc1 = {0.f,0.f,0.f,0.f};

  for (int ki = 0; ki < 4; ki++) {
    int k0 = ks0 + ki * 128;
    __syncthreads();
    for (int u = tid; u < 1024; u += 256) {       // X tile 64x128
      int row = u >> 4, cc = u & 15;
      ld8(&Xs[row][cc * 8], X, row * 4096 + k0 + cc * 8, xbf);
    }
    for (int u = tid; u < 512; u += 256) {        // W tile 32x128
      int row = u >> 4, cc = u & 15;
      ld8(&Ws[row][cc * 8], W, (wr0 + row) * 4096 + k0 + cc * 8, fbf);
    }
    __syncthreads();
    #pragma unroll
    for (int ks = 0; ks < 4; ks++) {
      bf16x8 af = *(const bf16x8*)&Xs[wv * 16 + lr][ks * 32 + lq * 8];
      bf16x8 b0 = *(const bf16x8*)&Ws[lr][ks * 32 + lq * 8];
      bf16x8 b1 = *(const bf16x8*)&Ws[16 + lr][ks * 32 + lq * 8];
      acc0 = MFMA16(af, b0, acc0);
      acc1 = MFMA16(af, b1, acc1);
    }
  }
  float* outp = out32 + (size_t)blockIdx.y * 64 * ostride;
  #pragma unroll
  for (int r = 0; r < 4; r++) {
    outp[(wv * 16 + lq * 4 + r) * ostride + n0 + lr]      = acc0[r];
    outp[(wv * 16 + lq * 4 + r) * ostride + n0 + 16 + lr] = acc1[r];
  }
}

// ---------------------------------------------------------------------------
// Prep: RoPE'd Q [bh][32][128], RoPE'd full-K [bh][64][128], V_full^T [bh][128][64]
// ---------------------------------------------------------------------------
__global__ __launch_bounds__(256) void prep_kernel(
    const float* __restrict__ Cq32, const void* __restrict__ kfp, const void* __restrict__ vfp,
    const float2* __restrict__ ctab, const int* __restrict__ flagp,
    u16* __restrict__ qrb, u16* __restrict__ kfullb, u16* __restrict__ vfullT)
{
  bool isbf = (*flagp != 0);
  int idx = blockIdx.x * 256 + threadIdx.x;       // 1,310,720 exact
  if (idx < 262144) {                              // qr
    int d = idx & 127, row = (idx >> 7) & 31, bh = idx >> 12;
    int b = bh >> 3, kvh = bh & 7, g = row >> 3, qp = row & 7;
    int tok = b * 8 + qp, h = kvh * 4 + g;
    float x  = c8(Cq32, tok * 6144 + h * 128 + d, 393216);
    float x2 = c8(Cq32, tok * 6144 + h * 128 + (d ^ 64), 393216);
    float2 cs = ctab[(4024 + qp) * 64 + (d & 63)];
    float sgn = (d < 64) ? -1.f : 1.f;
    qrb[idx] = f2bf(x * cs.x + sgn * (x2 * cs.y));
  } else if (idx < 786432) {                       // k_full roped, pos = 3968+t
    int j = idx - 262144;
    int d = j & 127, t = (j >> 7) & 63, bh = j >> 13;
    int b = bh >> 3, kvh = bh & 7;
    float x, x2;
    if (t < 56) {
      x  = ldf(kfp, (bh * 56 + t) * 128 + d, isbf);
      x2 = ldf(kfp, (bh * 56 + t) * 128 + (d ^ 64), isbf);
    } else {
      int tok = b * 8 + (t - 56);
      x  = c8(Cq32, tok * 6144 + 4096 + kvh * 128 + d, 393216);
      x2 = c8(Cq32, tok * 6144 + 4096 + kvh * 128 + (d ^ 64), 393216);
    }
    float2 cs = ctab[(3968 + t) * 64 + (d & 63)];
    float sgn = (d < 64) ? -1.f : 1.f;
    kfullb[j] = f2bf(x * cs.x + sgn * (x2 * cs.y));
  } else {                                         // v_full transposed [bh][d][t]
    int j = idx - 786432;
    int t = j & 63, d = (j >> 6) & 127, bh = j >> 13;
    int b = bh >> 3, kvh = bh & 7;
    float x;
    if (t < 56) x = ldf(vfp, (bh * 56 + t) * 128 + d, isbf);
    else        x = c8(Cq32, (b * 8 + t - 56) * 6144 + 5120 + kvh * 128 + d, 393216);
    vfullT[j] = f2bf(x);
  }
}

// ---------------------------------------------------------------------------
// Online-flash attention, 64-key chunks, 2 per block. Grid (64 bh, 32 grp).
// Chunks 0..61 quantized; chunk 62 = 64 full-precision keys; 63 skipped.
// NOTE: plain launch_bounds — (256,5) in R4 forced VGPR 48 and spilled ~75MB
// to scratch (WRITE_SIZE 8.4->92.7MB). Keep compiler free (~88 VGPR, no spill).
// LDS = 31232 B -> 5 blocks/CU.
// ---------------------------------------------------------------------------
__global__ __launch_bounds__(256) void attn_kernel(
    const int* __restrict__ kqw, const void* __restrict__ ksc, const void* __restrict__ kmn,
    const int* __restrict__ vqw, const void* __restrict__ vsc, const void* __restrict__ vmn,
    const u16* __restrict__ qrb, const u16* __restrict__ kfullb, const u16* __restrict__ vfullT,
    const float2* __restrict__ ctab, const int* __restrict__ flagp,
    u16* __restrict__ Opart, float* __restrict__ ml)
{
  bool isbf = (*flagp != 0);
  int bh = blockIdx.x, grp = blockIdx.y;
  int tid = threadIdx.x;

  __shared__ __align__(16) unsigned char L[31232];
  u16 (*Ktile)[136] = (u16(*)[136])L;              // [64][136]  17408 B (lifetime: B..C1)
  u16 (*Vtile)[72]  = (u16(*)[72])L;               // [128][72]  18432 B (lifetime: C1..loop-end)
  unsigned* rawK = (unsigned*)(L + 18432);         // [128][9]    4608 B (phase0..C1)
  float* sK  = (float*)(L + 23040);                // [128][3]
  float* sKm = (float*)(L + 24576);                // [128][3]
  unsigned* rawV = (unsigned*)(L + 18432);         // [64][17]    (C1..D, overlays rawK)
  float* sV  = (float*)(L + 22784);                // [64][5]
  float* sVm = (float*)(L + 24064);                // [64][5]
  u16 (*Pl)[72] = (u16(*)[72])(L + 26112);         // [32][72]    4608 (C1..loop-end)
  float* pmax = (float*)(L + 30720);               // [4][16]
  float* psum = (float*)(L + 30976);               // [4][16]

  int wv = tid >> 6, lane = tid & 63, lr = lane & 15, lq = lane >> 4;
  int mt = wv & 1, nh = wv >> 1;

  bf16x8 qa[4];
  #pragma unroll
  for (int ks = 0; ks < 4; ks++)
    qa[ks] = *(const bf16x8*)&qrb[(bh * 32 + mt * 16 + lr) * 128 + ks * 32 + lq * 8];

  float m_prev[4], l_run[4];
  #pragma unroll
  for (int r = 0; r < 4; r++) { m_prev[r] = -INFINITY; l_run[r] = 0.f; }
  f32x4 zf = {0.f,0.f,0.f,0.f};
  f32x4 oacc[4] = {zf, zf, zf, zf};

  for (int j = 0; j < 2; j++) {
    int c = grp * 2 + j;
    if (c >= 63) break;                            // uniform per block
    bool fullc = (c == 62);

    // ---- phase 0: coalesced raw K words + scales -> LDS ----
    if (!fullc) {
      #pragma unroll
      for (int it = 0; it < 4; it++) {
        int idx = tid + 256 * it;
        int d = idx >> 3, w = idx & 7;             // 8 lanes/row -> 32B segments
        rawK[d * 9 + w] = (unsigned)kqw[(bh * 128 + d) * 496 + c * 8 + w];
      }
      { int d = tid >> 1, gi = tid & 1;
        sK[d * 3 + gi]  = ldf(ksc, (bh * 128 + d) * 124 + c * 2 + gi, isbf);
        sKm[d * 3 + gi] = ldf(kmn, (bh * 128 + d) * 124 + c * 2 + gi, isbf); }
    }
    __syncthreads();                               // A
    // ---- dequant+RoPE K -> Ktile[t][d] (or stage full K) ----
    if (!fullc) {
      #pragma unroll
      for (int it = 0; it < 4; it++) {
        int idx = tid + 256 * it;
        int d = idx & 127, w = idx >> 7;           // w<8; lanes vary d
        unsigned w1 = rawK[d * 9 + w];
        unsigned w2 = rawK[(d ^ 64) * 9 + w];
        int gi = w >> 2;
        float sc1 = sK[d * 3 + gi],        m1 = sKm[d * 3 + gi];
        float sc2 = sK[(d ^ 64) * 3 + gi], m2 = sKm[(d ^ 64) * 3 + gi];
        int dm = d & 63;
        float sgn = (d < 64) ? -1.f : 1.f;
        const float2* ct = &ctab[(c * 64 + w * 8) * 64 + dm];
        #pragma unroll
        for (int i = 0; i < 8; i++) {
          float v1 = (float)((w1 >> (4 * i)) & 15u) * sc1 + m1;
          float v2 = (float)((w2 >> (4 * i)) & 15u) * sc2 + m2;
          float2 cs = ct[i * 64];
          Ktile[w * 8 + i][d] = f2bf(v1 * cs.x + sgn * (v2 * cs.y));
        }
      }
    } else {
      for (int u = tid; u < 1024; u += 256) {
        int row = u >> 4, cc = u & 15;
        *(uint4*)&Ktile[row][cc * 8] = *(const uint4*)&kfullb[(bh * 64 + row) * 128 + cc * 8];
      }
    }
    __syncthreads();                               // B
    // ---- S = Q.K^T : rows mt*16+, cols nh*32 + nt*16 + lr ----
    f32x4 sacc[2] = {zf, zf};
    #pragma unroll
    for (int ks = 0; ks < 4; ks++) {
      #pragma unroll
      for (int nt = 0; nt < 2; nt++) {
        bf16x8 bfr = *(const bf16x8*)&Ktile[nh * 32 + nt * 16 + lr][ks * 32 + lq * 8];
        sacc[nt] = MFMA16(qa[ks], bfr, sacc[nt]);
      }
    }
    // scale + wave-local row max
    float mx[4];
    #pragma unroll
    for (int r = 0; r < 4; r++) {
      sacc[0][r] *= 0.08838834764831845f;
      sacc[1][r] *= 0.08838834764831845f;
      mx[r] = fmaxf(sacc[0][r], sacc[1][r]);
    }
    #pragma unroll
    for (int m = 1; m < 16; m <<= 1) {
      #pragma unroll
      for (int r = 0; r < 4; r++) mx[r] = fmaxf(mx[r], __shfl_xor(mx[r], m));
    }
    if (lr == 0) {
      #pragma unroll
      for (int r = 0; r < 4; r++) pmax[wv * 16 + lq * 4 + r] = mx[r];
    }
    __syncthreads();                               // C1 (Ktile/rawK/sK dead)
    // ---- stage raw V + scales (overlay) / full V -> Vtile ----
    if (!fullc) {
      #pragma unroll
      for (int it = 0; it < 4; it++) {
        int idx = tid + 256 * it;                  // fully coalesced
        int t = idx >> 4, w = idx & 15;
        rawV[t * 17 + w] = (unsigned)vqw[(bh * 3968 + c * 64 + t) * 16 + w];
      }
      { int t = tid >> 2, gq = tid & 3;            // fully coalesced
        sV[t * 5 + gq]  = ldf(vsc, (bh * 3968 + c * 64 + t) * 4 + gq, isbf);
        sVm[t * 5 + gq] = ldf(vmn, (bh * 3968 + c * 64 + t) * 4 + gq, isbf); }
    } else {
      for (int u = tid; u < 1024; u += 256) {
        int d = u >> 3, t8 = u & 7;
        *(uint4*)&Vtile[d][t8 * 8] = *(const uint4*)&vfullT[(bh * 128 + d) * 64 + t8 * 8];
      }
    }
    // ---- online softmax: merge chunk max, exp, P write, partial sums ----
    float alpha[4], osum[4];
    #pragma unroll
    for (int r = 0; r < 4; r++) {
      float cm = fmaxf(mx[r], pmax[(wv ^ 2) * 16 + lq * 4 + r]);
      float mn2 = fmaxf(m_prev[r], cm);
      alpha[r] = __expf(m_prev[r] - mn2);          // 0 on first chunk
      m_prev[r] = mn2;
    }
    u16 pb[2][4];
    #pragma unroll
    for (int r = 0; r < 4; r++) {
      float p0 = __expf(sacc[0][r] - m_prev[r]);
      float p1 = __expf(sacc[1][r] - m_prev[r]);
      pb[0][r] = f2bf(p0); pb[1][r] = f2bf(p1);
      osum[r] = b2f(pb[0][r]) + b2f(pb[1][r]);     // sum what PV uses
    }
    #pragma unroll
    for (int m = 1; m < 16; m <<= 1) {
      #pragma unroll
      for (int r = 0; r < 4; r++) osum[r] += __shfl_xor(osum[r], m);
    }
    #pragma unroll
    for (int nt = 0; nt < 2; nt++)
      #pragma unroll
      for (int r = 0; r < 4; r++)
        Pl[mt * 16 + lq * 4 + r][nh * 32 + nt * 16 + lr] = pb[nt][r];
    if (lr == 0) {
      #pragma unroll
      for (int r = 0; r < 4; r++) psum[wv * 16 + lq * 4 + r] = osum[r];
    }
    __syncthreads();                               // C2
    // ---- dequant V -> Vtile[d][t] ----
    if (!fullc) {
      #pragma unroll
      for (int it = 0; it < 4; it++) {
        int idx = tid + 256 * it;
        int tl = idx & 63, w = idx >> 6;           // w<16; lanes vary t
        unsigned wd = rawV[tl * 17 + w];
        int gq = w >> 2;
        float sc = sV[tl * 5 + gq], mn = sVm[tl * 5 + gq];
        #pragma unroll
        for (int i = 0; i < 8; i++)
          Vtile[w * 8 + i][tl] = f2bf((float)((wd >> (4 * i)) & 15u) * sc + mn);
      }
    }
    // l update (partner psum ready at C2)
    #pragma unroll
    for (int r = 0; r < 4; r++)
      l_run[r] = l_run[r] * alpha[r] + osum[r] + psum[(wv ^ 2) * 16 + lq * 4 + r];
    __syncthreads();                               // D
    // ---- O = O*alpha + P.V ----
    f32x4 pv[4] = {zf, zf, zf, zf};
    #pragma unroll
    for (int ks = 0; ks < 2; ks++) {
      bf16x8 af = *(const bf16x8*)&Pl[mt * 16 + lr][ks * 32 + lq * 8];
      #pragma unroll
      for (int nt = 0; nt < 4; nt++) {
        bf16x8 bfr = *(const bf16x8*)&Vtile[nh * 64 + nt * 16 + lr][ks * 32 + lq * 8];
        pv[nt] = MFMA16(af, bfr, pv[nt]);
      }
    }
    #pragma unroll
    for (int nt = 0; nt < 4; nt++)
      #pragma unroll
      for (int r = 0; r < 4; r++)
        oacc[nt][r] = oacc[nt][r] * alpha[r] + pv[nt][r];
  }

  u16* Ob = Opart + (size_t)((bh * 32 + grp) * 32) * 128;
  #pragma unroll
  for (int nt = 0; nt < 4; nt++)
    #pragma unroll
    for (int r = 0; r < 4; r++)
      Ob[(mt * 16 + lq * 4 + r) * 128 + nh * 64 + nt * 16 + lr] = f2bf(oacc[nt][r]);
  if (wv < 2 && lr == 0) {
    #pragma unroll
    for (int r = 0; r < 4; r++) {
      ml[((bh * 32 + grp) * 32 + mt * 16 + lq * 4 + r) * 2 + 0] = m_prev[r];
      ml[((bh * 32 + grp) * 32 + mt * 16 + lq * 4 + r) * 2 + 1] = l_run[r];
    }
  }
}

// ---------------------------------------------------------------------------
// Combine 32 group partials per bh. Grid (64, 4 d-quarters).
// ---------------------------------------------------------------------------
__global__ __launch_bounds__(256) void combine_kernel(
    const u16* __restrict__ Opart, const float* __restrict__ ml, u16* __restrict__ attn_out)
{
  int bh = blockIdx.x, dq = blockIdx.y, tid = threadIdx.x;
  __shared__ float Wg[32][33];
  __shared__ float Ls[32];
  if (tid < 32) {
    int row = tid;
    float M = -INFINITY;
    for (int g = 0; g < 32; g++)
      M = fmaxf(M, ml[((bh * 32 + g) * 32 + row) * 2]);
    float Lacc = 0.f;
    for (int g = 0; g < 32; g++) {
      float m = ml[((bh * 32 + g) * 32 + row) * 2];
      float l = ml[((bh * 32 + g) * 32 + row) * 2 + 1];
      float w = __expf(m - M);
      Wg[g][row] = w;
      Lacc += l * w;
    }
    Ls[row] = Lacc;
  }
  __syncthreads();
  int row = tid >> 3, ds = tid & 7;
  int d0 = dq * 32 + ds * 4;
  float a0 = 0.f, a1 = 0.f, a2 = 0.f, a3 = 0.f;
  for (int g = 0; g < 32; g++) {
    float w = Wg[g][row];
    const u16* p = Opart + (size_t)((bh * 32 + g) * 32 + row) * 128 + d0;
    uint2 v = *(const uint2*)p;
    const u16* h = (const u16*)&v;
    a0 += w * b2f(h[0]); a1 += w * b2f(h[1]); a2 += w * b2f(h[2]); a3 += w * b2f(h[3]);
  }
  float inv = 1.0f / Ls[row];
  int b = bh >> 3, kvh = bh & 7, hg = row >> 3, qp = row & 7;
  u16* dst = attn_out + (size_t)(b * 8 + qp) * 4096 + (kvh * 4 + hg) * 128 + d0;
  dst[0] = f2bf(a0 * inv); dst[1] = f2bf(a1 * inv);
  dst[2] = f2bf(a2 * inv); dst[3] = f2bf(a3 * inv);
}

// ---------------------------------------------------------------------------
// Sum 8 Wo K-split partials, emit final output in detected dtype.
// ---------------------------------------------------------------------------
__global__ __launch_bounds__(256) void cast_kernel(
    const float* __restrict__ O32, const int* __restrict__ flagp, void* __restrict__ out)
{
  int i = blockIdx.x * 256 + threadIdx.x;          // 262144 exact
  float v = c8(O32, i, 262144);
  if (*flagp) ((u16*)out)[i] = f2bf(v);
  else        ((float*)out)[i] = v;
}

// ---------------------------------------------------------------------------
extern "C" void kernel_launch(void* const* d_in, const int* in_sizes, int n_in,
                              void* d_out, int out_size, void* d_ws, size_t ws_size,
                              hipStream_t stream)
{
  const void* hidden = d_in[0];
  const void* Wq  = d_in[1];
  const void* Wk  = d_in[2];
  const void* Wv  = d_in[3];
  const void* Wo  = d_in[4];
  const int*  kqw = (const int*)d_in[5];
  const void* ksc = d_in[6];
  const void* kmn = d_in[7];
  const void* kfp = d_in[8];
  const int*  vqw = (const int*)d_in[9];
  const void* vsc = d_in[10];
  const void* vmn = d_in[11];
  const void* vfp = d_in[12];

  char* ws = (char*)d_ws;
  int*    flag     = (int*)(ws);                    //        256
  float2* ctab     = (float2*)(ws + 256);           //  2,064,384
  float*  Cq32     = (float*)(ws + 2064640);        // regionA 16,777,216:
  u16*    Opart    = (u16*)(ws + 2064640);          //   Cq32 12.6MB / Opart 16.8MB / O32 8.4MB
  float*  O32      = (float*)(ws + 2064640);        //   (pairwise-disjoint lifetimes)
  u16*    qrb      = (u16*)(ws + 18841856);         //    524,288 (attn_out overlays)
  u16*    attn_out = qrb;
  u16*    kfullb   = (u16*)(ws + 19366144);         //  1,048,576
  u16*    vfullT   = (u16*)(ws + 20414720);         //  1,048,576
  float*  ml       = (float*)(ws + 21463296);       //    524,288  -> total ~22.0 MB

  ctab_kernel<<<1008, 256, 0, stream>>>((const u16*)hidden, flag, ctab);
  proj_kernel<<<dim3(192, 8), 256, 0, stream>>>(hidden, Wq, Wk, Wv, Cq32, 4096, 1024, 6144, flag, 1);
  prep_kernel<<<5120, 256, 0, stream>>>(Cq32, kfp, vfp, ctab, flag, qrb, kfullb, vfullT);
  attn_kernel<<<dim3(64, 32), 256, 0, stream>>>(kqw, ksc, kmn, vqw, vsc, vmn,
                                                qrb, kfullb, vfullT, ctab, flag, Opart, ml);
  combine_kernel<<<dim3(64, 4), 256, 0, stream>>>(Opart, ml, attn_out);
  proj_kernel<<<dim3(128, 8), 256, 0, stream>>>(attn_out, Wo, Wo, Wo, O32, 4096, 0, 4096, flag, 0);
  cast_kernel<<<1024, 256, 0, stream>>>(O32, flag, d_out);
}